// Round 16
// baseline (68.060 us; speedup 1.0000x reference)
//
#include <hip/hip_runtime.h>
#include <hip/hip_bf16.h>
#include <math.h>

#define NPTS 131072
#define DIM 32
#define MCL 256
#define NSTEP 18           // symmetric packing: 1 sq + 15 pair + 1 pair/lin + 1 lin/pad
#define BPTS 64            // points per block
#define THREADS 256

typedef __attribute__((ext_vector_type(8))) _Float16 f16x8;   // MFMA A/B fragment
typedef __attribute__((ext_vector_type(2))) _Float16 h2v;     // packed f16 pair
typedef __attribute__((ext_vector_type(2))) unsigned u2v;     // 2 dwords (4 f16)
typedef __attribute__((ext_vector_type(4))) float f32x4;

__device__ __forceinline__ short f2h(float f) {
    _Float16 h = (_Float16)f;
    union { _Float16 h; short s; } X; X.h = h; return X.s;
}

// ---------------------------------------------------------------------------
// prep (256 threads/cluster): symmetric-packed G (f16):
//  step 0           : c = E[k][k]                (squares; E = LL^T - I)
//  steps 1..15      : c = 2*E[k][(k+s)&31]       (pairs, circular diff s)
//  step 16, k<16    : c = 2*E[k][k+16]           (diff-16 pairs)
//  step 16, k>=16   : c = -2*Ac[k-16]            (linear)
//  step 17, k<16    : c = -2*Ac[k+16]            (linear)
//  step 17, k>=16   : c = 0                      (pad)
// G addr (shorts): s*8192 + (m>>4)*512 + (k>>3)*128 + (m&15)*8 + (k&7)
// logdet: register GE on wave 0 (col-per-lane, unrolled, no pivot).
// ---------------------------------------------------------------------------
__global__ __launch_bounds__(256) void gmm_prep(
    const float* __restrict__ center,
    const float* __restrict__ L,
    const float* __restrict__ weight,
    short* __restrict__ G,
    float* __restrict__ cst)
{
    const int m = blockIdx.x;
    const int t = threadIdx.x;
    __shared__ float Ls[DIM][DIM + 1];
    __shared__ float As[DIM][DIM + 1];
    __shared__ float Acs[DIM];
    __shared__ float red[DIM];

    const float* Lm = L + m * DIM * DIM;
    for (int k = t; k < DIM * DIM; k += 256)
        Ls[k >> 5][k & 31] = Lm[k];
    __syncthreads();

    // A = L L^T  (4 elems/thread)
    for (int idx = t; idx < DIM * DIM; idx += 256) {
        const int j = idx >> 5, l = idx & 31;
        float a = 0.f;
        #pragma unroll
        for (int d = 0; d < DIM; ++d) a = fmaf(Ls[j][d], Ls[l][d], a);
        As[j][l] = a;
    }
    __syncthreads();

    if (t < DIM) {
        float a = 0.f;
        #pragma unroll
        for (int l = 0; l < DIM; ++l) a = fmaf(As[t][l], center[m * DIM + l], a);
        Acs[t] = a;
        red[t] = a * center[m * DIM + t];
    }
    __syncthreads();

    const int mt = m >> 4, ml = m & 15;
    for (int idx = t; idx < NSTEP * 32; idx += 256) {
        const int s = idx >> 5, k = idx & 31;
        float c;
        if (s == 0)       c = As[k][k] - 1.0f;
        else if (s <= 15) c = 2.0f * As[k][(k + s) & 31];
        else if (s == 16) c = (k < 16) ? 2.0f * As[k][k + 16] : -2.0f * Acs[k - 16];
        else              c = (k < 16) ? -2.0f * Acs[k + 16] : 0.0f;
        G[s * 8192 + mt * 512 + (k >> 3) * 128 + ml * 8 + (k & 7)] = f2h(c);
    }

    if (t < 64) {
        // register GE, no pivot: lane j owns column j.
        float logdet = 0.f;
        if (t < DIM) {
            float col[DIM];
            #pragma unroll
            for (int r2 = 0; r2 < DIM; ++r2) col[r2] = Ls[r2][t];
            float prodabs = 1.0f;
            #pragma unroll
            for (int k = 0; k < DIM; ++k) {
                const float pv  = __shfl(col[k], k, 64);
                const float rpv = 1.0f / pv;
                const float cjk = col[k];
                #pragma unroll
                for (int t2 = k + 1; t2 < DIM; ++t2) {
                    const float f = __shfl(col[t2], k, 64) * rpv;
                    col[t2] = fmaf(-f, cjk, col[t2]);
                }
                prodabs *= fabsf(pv);
            }
            logdet = logf(prodabs);
        }

        float wsp = 0.f;
        for (int j = t; j < MCL; j += 64) wsp += fabsf(weight[j]);
        #pragma unroll
        for (int d2 = 1; d2 < 64; d2 <<= 1) wsp += __shfl_xor(wsp, d2, 64);

        if (t == 0) {
            float t3 = 0.f;
            #pragma unroll
            for (int j = 0; j < DIM; ++j) t3 += red[j];
            cst[m] = logf(fabsf(weight[m])) - logf(wsp) + logdet - 0.5f * t3;
        }
    }
}

// ---------------------------------------------------------------------------
// main kernel helpers: compile-time pair selection; packed f16 math (R12).
// ---------------------------------------------------------------------------
template<int J>
__device__ __forceinline__ unsigned wword(const u2v b0, const u2v b1, const u2v b2) {
    if constexpr (J < 2)      return b0[J];
    else if constexpr (J < 4) return b1[J - 2];
    else                      return b2[J - 4];
}

template<int OFF2, int Q>
__device__ __forceinline__ h2v wpair(const u2v b0, const u2v b1, const u2v b2) {
    constexpr int idx0 = OFF2 + 2 * Q;
    constexpr int wj = idx0 >> 1;
    unsigned u;
    if constexpr ((idx0 & 1) == 0)
        u = wword<wj>(b0, b1, b2);
    else
        u = __builtin_amdgcn_alignbit(wword<wj + 1>(b0, b1, b2),
                                      wword<wj>(b0, b1, b2), 16);
    union { unsigned u; h2v h; } X; X.u = u; return X.h;
}

template<int S, int Q, int OFF2>
__device__ __forceinline__ h2v mkpair(const h2v (&xp)[4], int kg,
                                      const u2v b0, const u2v b1, const u2v b2) {
    if constexpr (S == 0) {
        return xp[Q] * xp[Q];                    // squares: window == own slice
    } else {
        const h2v wp = wpair<OFF2, Q>(b0, b1, b2);
        if constexpr (S == 16) {
            return (kg < 2) ? (h2v)(xp[Q] * wp) : wp;   // pairs | linear
        } else if constexpr (S == 17) {
            const h2v z = { (_Float16)0.f, (_Float16)0.f };
            return (kg < 2) ? wp : z;                    // linear | pad
        } else {
            return xp[Q] * wp;
        }
    }
}

// ---------------------------------------------------------------------------
// main: block = 64 pts x 256 cl, 4 waves; WAVE = 64-COLUMN SLICE (rows
// shared), tile 64x64, acc[4][4] = 64 AGPR -> 3 waves/SIMD (~140 regs,
// < 170 cap; R8 discipline). R15 diagnosis: 2 waves/SIMD can't hide the
// dependency stalls; 64x64 col-split gives 12 waves/CU with per-CU B
// traffic 48 KB/step (below the ~60 B/cyc L1/L2 ceiling that killed R14's
// 3-wave attempt). A-gen duplicated 4x across waves but it's the cheap f16
// path now (R9's failure was bf16 A-gen cost, fixed in R12). j-outer MFMA
// order: bf[j] refills right after its last reader -> ~500-cyc load window.
// ---------------------------------------------------------------------------
template<int S>
__device__ __forceinline__ void k_step(
    const short* __restrict__ gw,      // G + w*2048 + lane*8 (shorts)
    const short* __restrict__ Xh,
    const int (&rowh)[4],
    const h2v (&xp)[4][4],
    f16x8 (&bf)[4],
    f32x4 (&acc)[4][4],
    int kg)
{
    constexpr int shv  = (S == 17) ? 16 : S;
    constexpr int off2 = shv & 3;
    const int bq = ((kg * 8 + shv) & 31) & ~3;   // aligned 4-half base

    f16x8 af[4];
    #pragma unroll
    for (int i = 0; i < 4; ++i) {
        u2v b0 = {}, b1 = {}, b2 = {};
        if constexpr (S != 0) {
            const short* xr = Xh + rowh[i] + bq;
            b0 = *(const u2v*)(xr);
            b1 = *(const u2v*)(xr + 4);
            if constexpr (off2 != 0) b2 = *(const u2v*)(xr + 8);
        }
        union { f16x8 v; h2v p[4]; } U;
        U.p[0] = mkpair<S, 0, off2>(xp[i], kg, b0, b1, b2);
        U.p[1] = mkpair<S, 1, off2>(xp[i], kg, b0, b1, b2);
        U.p[2] = mkpair<S, 2, off2>(xp[i], kg, b0, b1, b2);
        U.p[3] = mkpair<S, 3, off2>(xp[i], kg, b0, b1, b2);
        af[i] = U.v;
    }

    // j-outer: all readers of bf[j] complete, then bf[j] refills for S+1 --
    // the j=0 load gets ~12 MFMAs of wall-time before its first use.
    #pragma unroll
    for (int j = 0; j < 4; ++j) {
        #pragma unroll
        for (int i = 0; i < 4; ++i)
            acc[i][j] = __builtin_amdgcn_mfma_f32_16x16x32_f16(
                af[i], bf[j], acc[i][j], 0, 0, 0);
        if constexpr (S + 1 < NSTEP)
            bf[j] = *(const f16x8*)(gw + (size_t)(S + 1) * 8192 + j * 512);
    }
    __builtin_amdgcn_sched_barrier(0);   // keep step regions separate (R7 lesson)
}

template<int S>
__device__ __forceinline__ void k_loop(
    const short* __restrict__ gw, const short* __restrict__ Xh,
    const int (&rowh)[4], const h2v (&xp)[4][4],
    f16x8 (&bf)[4], f32x4 (&acc)[4][4], int kg)
{
    k_step<S>(gw, Xh, rowh, xp, bf, acc, kg);
    if constexpr (S + 1 < NSTEP)
        k_loop<S + 1>(gw, Xh, rowh, xp, bf, acc, kg);
}

__global__ __launch_bounds__(THREADS, 3) void gmm_mfma(
    const float* __restrict__ X,
    const short* __restrict__ G,
    const float* __restrict__ cstw,
    const float* __restrict__ thr,
    float* __restrict__ out)
{
    __shared__ __attribute__((aligned(16))) short Xh[BPTS * 44]; // 5.5 KB (f16)
    __shared__ float nrm_s[BPTS];
    __shared__ float cst_s[MCL];
    __shared__ float lse_m[4][BPTS];
    __shared__ float lse_d[4][BPTS];

    const int tid  = threadIdx.x;
    const int lane = tid & 63;
    const int w    = tid >> 6;     // wave 0..3 = 64-col slice
    const int r    = lane & 15;
    const int kg   = lane >> 4;    // k-group 0..3
    const int P0   = blockIdx.x * BPTS;

    // per-wave B pointer: col-tiles w*4 .. w*4+3, this lane's 8 f16
    const short* gw = G + w * 2048 + lane * 8;

    // resident x-slices -> packed f16 pairs (4 row-fragments, rows shared)
    int rowh[4];
    h2v xp[4][4];
    #pragma unroll
    for (int i = 0; i < 4; ++i) {
        const int row = i * 16 + r;
        rowh[i] = row * 44;
        const float4* xg = reinterpret_cast<const float4*>(
            X + (size_t)(P0 + row) * DIM + kg * 8);
        const float4 a = xg[0], b = xg[1];
        xp[i][0] = h2v{ (_Float16)a.x, (_Float16)a.y };
        xp[i][1] = h2v{ (_Float16)a.z, (_Float16)a.w };
        xp[i][2] = h2v{ (_Float16)b.x, (_Float16)b.y };
        xp[i][3] = h2v{ (_Float16)b.z, (_Float16)b.w };
    }

    // stage Xh (f16, +8 dup for circular wrap) + row norms (64 rows, tid<128)
    {
        const int p = tid >> 1, hf = tid & 1;
        if (tid < 128) {
            const float4* Xg = reinterpret_cast<const float4*>(
                X + (size_t)(P0 + p) * DIM + hf * 16);
            float part = 0.f;
            #pragma unroll
            for (int q = 0; q < 4; ++q) {
                const float4 v = Xg[q];
                const int kb = hf * 16 + 4 * q;
                Xh[p * 44 + kb + 0] = f2h(v.x);
                Xh[p * 44 + kb + 1] = f2h(v.y);
                Xh[p * 44 + kb + 2] = f2h(v.z);
                Xh[p * 44 + kb + 3] = f2h(v.w);
                if (!hf && q < 2) {
                    Xh[p * 44 + 32 + kb + 0] = f2h(v.x);
                    Xh[p * 44 + 32 + kb + 1] = f2h(v.y);
                    Xh[p * 44 + 32 + kb + 2] = f2h(v.z);
                    Xh[p * 44 + 32 + kb + 3] = f2h(v.w);
                }
                part = fmaf(v.x, v.x, part); part = fmaf(v.y, v.y, part);
                part = fmaf(v.z, v.z, part); part = fmaf(v.w, v.w, part);
            }
            part += __shfl_xor(part, 1, 64);
            if (!hf) nrm_s[p] = part;
        }
        cst_s[tid] = cstw[tid];
    }

    // prologue: load step-0 B fragments
    f16x8 bf[4];
    #pragma unroll
    for (int j = 0; j < 4; ++j)
        bf[j] = *(const f16x8*)(gw + j * 512);

    __syncthreads();   // Xh/nrm/cst visible to all waves

    f32x4 acc[4][4] = {};
    k_loop<0>(gw, Xh, rowh, xp, bf, acc, kg);

    // ---- epilogue: weighted LSE over this wave's 64 clusters.
    // Butterfly max first, one exp pass, butterfly add (R12 pattern).
    float cstr[4];
    #pragma unroll
    for (int j = 0; j < 4; ++j)
        cstr[j] = cst_s[w * 64 + j * 16 + r];

    float mx[16], sm[16];
    #pragma unroll
    for (int i = 0; i < 4; ++i)
        #pragma unroll
        for (int rg = 0; rg < 4; ++rg) {
            const int sl = i * 4 + rg;
            float m_ = -1e30f;
            #pragma unroll
            for (int j = 0; j < 4; ++j)
                m_ = fmaxf(m_, fmaf(acc[i][j][rg], -0.5f, cstr[j]));
            #pragma unroll
            for (int d = 1; d < 16; d <<= 1)
                m_ = fmaxf(m_, __shfl_xor(m_, d, 64));
            float s_ = 0.f;
            #pragma unroll
            for (int j = 0; j < 4; ++j)
                s_ += __expf(fmaf(acc[i][j][rg], -0.5f, cstr[j]) - m_);
            #pragma unroll
            for (int d = 1; d < 16; d <<= 1)
                s_ += __shfl_xor(s_, d, 64);
            mx[sl] = m_; sm[sl] = s_;
        }

    // per-wave partials -> LDS
    if (r == 0) {
        #pragma unroll
        for (int i = 0; i < 4; ++i)
            #pragma unroll
            for (int rg = 0; rg < 4; ++rg) {
                const int p2 = i * 16 + kg * 4 + rg;
                lse_m[w][p2] = mx[i * 4 + rg];
                lse_d[w][p2] = sm[i * 4 + rg];
            }
    }
    __syncthreads();

    // final merge of the 4 wave partials
    if (tid < BPTS) {
        float m = lse_m[0][tid], s = lse_d[0][tid];
        #pragma unroll
        for (int w2 = 1; w2 < 4; ++w2) {
            const float pm = lse_m[w2][tid], ps = lse_d[w2][tid];
            const float nm = fmaxf(m, pm);
            s = s * __expf(m - nm) + ps * __expf(pm - nm);
            m = nm;
        }
        out[P0 + tid] = m + __logf(s) - 0.5f * nrm_s[tid] - thr[0];
    }
}

extern "C" void kernel_launch(void* const* d_in, const int* in_sizes, int n_in,
                              void* d_out, int out_size, void* d_ws, size_t ws_size,
                              hipStream_t stream)
{
    const float* X      = (const float*)d_in[0];
    const float* center = (const float*)d_in[1];
    const float* L      = (const float*)d_in[2];
    const float* weight = (const float*)d_in[3];
    const float* thr    = (const float*)d_in[4];
    float* out = (float*)d_out;

    // ws layout: cst [256] f32 | G [18*8192] f16-as-short (~296 KB)
    float* cst = (float*)d_ws;
    short* G   = (short*)((char*)d_ws + 1024);

    gmm_prep<<<MCL, 256, 0, stream>>>(center, L, weight, G, cst);
    gmm_mfma<<<NPTS / BPTS, THREADS, 0, stream>>>(X, G, cst, thr, out);
}

// Round 17
// 63.934 us; speedup vs baseline: 1.0645x; 1.0645x over previous
//
#include <hip/hip_runtime.h>
#include <hip/hip_bf16.h>
#include <math.h>

#define NPTS 131072
#define DIM 32
#define MCL 256
#define NSTEP 18           // symmetric packing: 1 sq + 15 pair + 1 pair/lin + 1 lin/pad
#define BPTS 128           // points per block
#define THREADS 256

typedef __attribute__((ext_vector_type(8))) _Float16 f16x8;   // MFMA A/B fragment
typedef __attribute__((ext_vector_type(2))) _Float16 h2v;     // packed f16 pair
typedef __attribute__((ext_vector_type(2))) unsigned u2v;     // 2 dwords (4 f16)
typedef __attribute__((ext_vector_type(4))) float f32x4;

__device__ __forceinline__ short f2h(float f) {
    _Float16 h = (_Float16)f;
    union { _Float16 h; short s; } X; X.h = h; return X.s;
}

// ---------------------------------------------------------------------------
// prep (256 threads/cluster): symmetric-packed G (f16):
//  step 0           : c = E[k][k]                (squares; E = LL^T - I)
//  steps 1..15      : c = 2*E[k][(k+s)&31]       (pairs, circular diff s)
//  step 16, k<16    : c = 2*E[k][k+16]           (diff-16 pairs)
//  step 16, k>=16   : c = -2*Ac[k-16]            (linear)
//  step 17, k<16    : c = -2*Ac[k+16]            (linear)
//  step 17, k>=16   : c = 0                      (pad)
// G addr (shorts): s*8192 + (m>>4)*512 + (k>>3)*128 + (m&15)*8 + (k&7)
// logdet: register GE on wave 0 (col-per-lane, unrolled, no pivot).
// ---------------------------------------------------------------------------
__global__ __launch_bounds__(256) void gmm_prep(
    const float* __restrict__ center,
    const float* __restrict__ L,
    const float* __restrict__ weight,
    short* __restrict__ G,
    float* __restrict__ cst)
{
    const int m = blockIdx.x;
    const int t = threadIdx.x;
    __shared__ float Ls[DIM][DIM + 1];
    __shared__ float As[DIM][DIM + 1];
    __shared__ float Acs[DIM];
    __shared__ float red[DIM];

    const float* Lm = L + m * DIM * DIM;
    for (int k = t; k < DIM * DIM; k += 256)
        Ls[k >> 5][k & 31] = Lm[k];
    __syncthreads();

    // A = L L^T  (4 elems/thread)
    for (int idx = t; idx < DIM * DIM; idx += 256) {
        const int j = idx >> 5, l = idx & 31;
        float a = 0.f;
        #pragma unroll
        for (int d = 0; d < DIM; ++d) a = fmaf(Ls[j][d], Ls[l][d], a);
        As[j][l] = a;
    }
    __syncthreads();

    if (t < DIM) {
        float a = 0.f;
        #pragma unroll
        for (int l = 0; l < DIM; ++l) a = fmaf(As[t][l], center[m * DIM + l], a);
        Acs[t] = a;
        red[t] = a * center[m * DIM + t];
    }
    __syncthreads();

    const int mt = m >> 4, ml = m & 15;
    for (int idx = t; idx < NSTEP * 32; idx += 256) {
        const int s = idx >> 5, k = idx & 31;
        float c;
        if (s == 0)       c = As[k][k] - 1.0f;
        else if (s <= 15) c = 2.0f * As[k][(k + s) & 31];
        else if (s == 16) c = (k < 16) ? 2.0f * As[k][k + 16] : -2.0f * Acs[k - 16];
        else              c = (k < 16) ? -2.0f * Acs[k + 16] : 0.0f;
        G[s * 8192 + mt * 512 + (k >> 3) * 128 + ml * 8 + (k & 7)] = f2h(c);
    }

    if (t < 64) {
        // register GE, no pivot: lane j owns column j.
        float logdet = 0.f;
        if (t < DIM) {
            float col[DIM];
            #pragma unroll
            for (int r2 = 0; r2 < DIM; ++r2) col[r2] = Ls[r2][t];
            float prodabs = 1.0f;
            #pragma unroll
            for (int k = 0; k < DIM; ++k) {
                const float pv  = __shfl(col[k], k, 64);
                const float rpv = 1.0f / pv;
                const float cjk = col[k];
                #pragma unroll
                for (int t2 = k + 1; t2 < DIM; ++t2) {
                    const float f = __shfl(col[t2], k, 64) * rpv;
                    col[t2] = fmaf(-f, cjk, col[t2]);
                }
                prodabs *= fabsf(pv);
            }
            logdet = logf(prodabs);
        }

        float wsp = 0.f;
        for (int j = t; j < MCL; j += 64) wsp += fabsf(weight[j]);
        #pragma unroll
        for (int d2 = 1; d2 < 64; d2 <<= 1) wsp += __shfl_xor(wsp, d2, 64);

        if (t == 0) {
            float t3 = 0.f;
            #pragma unroll
            for (int j = 0; j < DIM; ++j) t3 += red[j];
            cst[m] = logf(fabsf(weight[m])) - logf(wsp) + logdet - 0.5f * t3;
        }
    }
}

// ---------------------------------------------------------------------------
// main kernel helpers. With the dual-shifted LDS copy, every window read has
// an EVEN sub-offset (0 or 2) -> wpair never needs alignbit.
// ---------------------------------------------------------------------------
template<int J>
__device__ __forceinline__ unsigned wword(const u2v b0, const u2v b1, const u2v b2) {
    if constexpr (J < 2)      return b0[J];
    else if constexpr (J < 4) return b1[J - 2];
    else                      return b2[J - 4];
}

template<int OFF2, int Q>
__device__ __forceinline__ h2v wpair(const u2v b0, const u2v b1, const u2v b2) {
    static_assert((OFF2 & 1) == 0, "odd offsets eliminated by XhO copy");
    constexpr int wj = (OFF2 + 2 * Q) >> 1;
    union { unsigned u; h2v h; } X; X.u = wword<wj>(b0, b1, b2); return X.h;
}

template<int S, int Q, int OFF2>
__device__ __forceinline__ h2v mkpair(const h2v (&xp)[4], int kg,
                                      const u2v b0, const u2v b1, const u2v b2) {
    if constexpr (S == 0) {
        return xp[Q] * xp[Q];                    // squares: window == own slice
    } else {
        const h2v wp = wpair<OFF2, Q>(b0, b1, b2);
        if constexpr (S == 16) {
            return (kg < 2) ? (h2v)(xp[Q] * wp) : wp;   // pairs | linear
        } else if constexpr (S == 17) {
            const h2v z = { (_Float16)0.f, (_Float16)0.f };
            return (kg < 2) ? wp : z;                    // linear | pad
        } else {
            return xp[Q] * wp;
        }
    }
}

// ---------------------------------------------------------------------------
// main: R15 structure (block = 128 pts x 256 cl, 4 waves, wave tile 64x128,
// acc[4][8] = 128 AGPR, 2 waves/SIMD, reg-resident B) + two refinements:
// (1) j-outer bf refill: bf[j] reloads right after its last reader -> each
//     L1 load gets ~3/4 of a step to land (R15 gave it ~50 cyc).
// (2) dual-shifted Xh: XhO[i] = x[(i+1)&31]; odd shifts read XhO at an even
//     sub-offset -> ZERO v_alignbit in the whole K-loop (was 4/frag on 8
//     of 17 steps), and one fewer ds_read on those steps.
// Reg budget unchanged (~252/256 at launch_bounds(256,2), R8 discipline).
// ---------------------------------------------------------------------------
template<int S>
__device__ __forceinline__ void k_step(
    const short* __restrict__ gw,      // G + wc*4096 + lane*8 (shorts)
    const short* __restrict__ Xh,
    const short* __restrict__ XhO,
    const int (&rowh)[4],
    const h2v (&xp)[4][4],
    f16x8 (&bf)[8],
    f32x4 (&acc)[4][8],
    int kg)
{
    constexpr int shv  = (S == 17) ? 16 : S;
    constexpr bool odd = (shv & 1) != 0;
    constexpr int sh2  = odd ? (shv - 1) : shv;     // shift within chosen copy
    constexpr int off2 = sh2 & 3;                   // 0 or 2 -> no alignbit
    const int bq = ((kg * 8 + sh2) & 31) & ~3;      // aligned 4-half base

    f16x8 af[4];
    #pragma unroll
    for (int i = 0; i < 4; ++i) {
        u2v b0 = {}, b1 = {}, b2 = {};
        if constexpr (S != 0) {
            const short* xr = (odd ? XhO : Xh) + rowh[i] + bq;
            b0 = *(const u2v*)(xr);
            b1 = *(const u2v*)(xr + 4);
            if constexpr (off2 != 0) b2 = *(const u2v*)(xr + 8);
        }
        union { f16x8 v; h2v p[4]; } U;
        U.p[0] = mkpair<S, 0, off2>(xp[i], kg, b0, b1, b2);
        U.p[1] = mkpair<S, 1, off2>(xp[i], kg, b0, b1, b2);
        U.p[2] = mkpair<S, 2, off2>(xp[i], kg, b0, b1, b2);
        U.p[3] = mkpair<S, 3, off2>(xp[i], kg, b0, b1, b2);
        af[i] = U.v;
    }

    // j-outer: all 4 readers of bf[j] run, then bf[j] refills for S+1 --
    // the j=0 load has 28 MFMAs of wall-time before its next use.
    #pragma unroll
    for (int j = 0; j < 8; ++j) {
        #pragma unroll
        for (int i = 0; i < 4; ++i)
            acc[i][j] = __builtin_amdgcn_mfma_f32_16x16x32_f16(
                af[i], bf[j], acc[i][j], 0, 0, 0);
        if constexpr (S + 1 < NSTEP)
            bf[j] = *(const f16x8*)(gw + (size_t)(S + 1) * 8192 + j * 512);
    }
    __builtin_amdgcn_sched_barrier(0);   // keep step regions separate (R7 lesson)
}

template<int S>
__device__ __forceinline__ void k_loop(
    const short* __restrict__ gw, const short* __restrict__ Xh,
    const short* __restrict__ XhO,
    const int (&rowh)[4], const h2v (&xp)[4][4],
    f16x8 (&bf)[8], f32x4 (&acc)[4][8], int kg)
{
    k_step<S>(gw, Xh, XhO, rowh, xp, bf, acc, kg);
    if constexpr (S + 1 < NSTEP)
        k_loop<S + 1>(gw, Xh, XhO, rowh, xp, bf, acc, kg);
}

__global__ __launch_bounds__(THREADS, 2) void gmm_mfma(
    const float* __restrict__ X,
    const short* __restrict__ G,
    const float* __restrict__ cstw,
    const float* __restrict__ thr,
    float* __restrict__ out)
{
    __shared__ __attribute__((aligned(16))) short Xh[BPTS * 44];  // 11.3 KB
    __shared__ __attribute__((aligned(16))) short XhO[BPTS * 44]; // 11.3 KB
    __shared__ float nrm_s[BPTS];
    __shared__ float cst_s[MCL];
    __shared__ float lse_m[BPTS];
    __shared__ float lse_d[BPTS];

    const int tid  = threadIdx.x;
    const int lane = tid & 63;
    const int w    = tid >> 6;     // wave 0..3
    const int wr   = w & 1;        // row half: 64 points
    const int wc   = w >> 1;       // col half: 128 clusters
    const int r    = lane & 15;
    const int kg   = lane >> 4;
    const int P0   = blockIdx.x * BPTS;

    // per-wave B pointer: cols wc*128.., this lane's 8 f16
    const short* gw = G + wc * 4096 + lane * 8;

    // resident x-slices -> packed f16 pairs (4 row-fragments of 16)
    int rowh[4];
    h2v xp[4][4];
    #pragma unroll
    for (int i = 0; i < 4; ++i) {
        const int row = wr * 64 + i * 16 + r;
        rowh[i] = row * 44;
        const float4* xg = reinterpret_cast<const float4*>(
            X + (size_t)(P0 + row) * DIM + kg * 8);
        const float4 a = xg[0], b = xg[1];
        xp[i][0] = h2v{ (_Float16)a.x, (_Float16)a.y };
        xp[i][1] = h2v{ (_Float16)a.z, (_Float16)a.w };
        xp[i][2] = h2v{ (_Float16)b.x, (_Float16)b.y };
        xp[i][3] = h2v{ (_Float16)b.z, (_Float16)b.w };
    }

    // stage Xh (x[k]) and XhO (x[(k+1)&31]), both +8 dup for wrap; row norms
    {
        const int p = tid >> 1, hf = tid & 1;
        const float4* Xg = reinterpret_cast<const float4*>(
            X + (size_t)(P0 + p) * DIM + hf * 16);
        float part = 0.f;
        #pragma unroll
        for (int q = 0; q < 4; ++q) {
            const float4 v = Xg[q];
            const int kb = hf * 16 + 4 * q;
            const short h0 = f2h(v.x), h1 = f2h(v.y), h2 = f2h(v.z), h3 = f2h(v.w);
            Xh[p * 44 + kb + 0] = h0;
            Xh[p * 44 + kb + 1] = h1;
            Xh[p * 44 + kb + 2] = h2;
            Xh[p * 44 + kb + 3] = h3;
            if (!hf && q < 2) {
                Xh[p * 44 + 32 + kb + 0] = h0;
                Xh[p * 44 + 32 + kb + 1] = h1;
                Xh[p * 44 + 32 + kb + 2] = h2;
                Xh[p * 44 + 32 + kb + 3] = h3;
            }
            // XhO[i] = x[(i+1)&31]  ->  x[k] lands at i = (k-1)&31
            const int i0 = (kb - 1) & 31;
            XhO[p * 44 + i0] = h0;
            XhO[p * 44 + kb + 0] = h1;
            XhO[p * 44 + kb + 1] = h2;
            XhO[p * 44 + kb + 2] = h3;
            if (i0 < 8)       XhO[p * 44 + 32 + i0] = h0;
            if (kb + 0 < 8) { XhO[p * 44 + 32 + kb + 0] = h1; }
            if (kb + 1 < 8) { XhO[p * 44 + 32 + kb + 1] = h2; }
            if (kb + 2 < 8) { XhO[p * 44 + 32 + kb + 2] = h3; }
            part = fmaf(v.x, v.x, part); part = fmaf(v.y, v.y, part);
            part = fmaf(v.z, v.z, part); part = fmaf(v.w, v.w, part);
        }
        part += __shfl_xor(part, 1, 64);
        if (!hf) nrm_s[p] = part;
        cst_s[tid] = cstw[tid];
    }

    // prologue: load step-0 B fragments
    f16x8 bf[8];
    #pragma unroll
    for (int j = 0; j < 8; ++j)
        bf[j] = *(const f16x8*)(gw + j * 512);

    __syncthreads();   // Xh/XhO/nrm/cst visible to all waves

    f32x4 acc[4][8] = {};
    k_loop<0>(gw, Xh, XhO, rowh, xp, bf, acc, kg);

    // ---- epilogue: weighted LSE over this wave's 128 clusters.
    // Butterfly max first, one exp pass, butterfly add (R12 pattern).
    float cstr[8];
    #pragma unroll
    for (int j = 0; j < 8; ++j)
        cstr[j] = cst_s[wc * 128 + j * 16 + r];

    float mx[16], sm[16];
    #pragma unroll
    for (int i = 0; i < 4; ++i)
        #pragma unroll
        for (int rg = 0; rg < 4; ++rg) {
            const int sl = i * 4 + rg;
            float m_ = -1e30f;
            #pragma unroll
            for (int j = 0; j < 8; ++j)
                m_ = fmaxf(m_, fmaf(acc[i][j][rg], -0.5f, cstr[j]));
            #pragma unroll
            for (int d = 1; d < 16; d <<= 1)
                m_ = fmaxf(m_, __shfl_xor(m_, d, 64));
            float s_ = 0.f;
            #pragma unroll
            for (int j = 0; j < 8; ++j)
                s_ += __expf(fmaf(acc[i][j][rg], -0.5f, cstr[j]) - m_);
            #pragma unroll
            for (int d = 1; d < 16; d <<= 1)
                s_ += __shfl_xor(s_, d, 64);
            mx[sl] = m_; sm[sl] = s_;
        }

    // cross col-half merge via LDS
    if (wc == 0 && r == 0) {
        #pragma unroll
        for (int i = 0; i < 4; ++i)
            #pragma unroll
            for (int rg = 0; rg < 4; ++rg) {
                const int p2 = wr * 64 + i * 16 + kg * 4 + rg;
                lse_m[p2] = mx[i * 4 + rg];
                lse_d[p2] = sm[i * 4 + rg];
            }
    }
    __syncthreads();
    if (wc == 1 && r == 0) {
        const float thrv = thr[0];
        #pragma unroll
        for (int i = 0; i < 4; ++i)
            #pragma unroll
            for (int rg = 0; rg < 4; ++rg) {
                const int sl = i * 4 + rg;
                const int p2 = wr * 64 + i * 16 + kg * 4 + rg;
                const float om = lse_m[p2], os = lse_d[p2];
                const float nm = fmaxf(mx[sl], om);
                const float ss = sm[sl] * __expf(mx[sl] - nm) + os * __expf(om - nm);
                out[P0 + p2] = nm + __logf(ss) - 0.5f * nrm_s[p2] - thrv;
            }
    }
}

extern "C" void kernel_launch(void* const* d_in, const int* in_sizes, int n_in,
                              void* d_out, int out_size, void* d_ws, size_t ws_size,
                              hipStream_t stream)
{
    const float* X      = (const float*)d_in[0];
    const float* center = (const float*)d_in[1];
    const float* L      = (const float*)d_in[2];
    const float* weight = (const float*)d_in[3];
    const float* thr    = (const float*)d_in[4];
    float* out = (float*)d_out;

    // ws layout: cst [256] f32 | G [18*8192] f16-as-short (~296 KB)
    float* cst = (float*)d_ws;
    short* G   = (short*)((char*)d_ws + 1024);

    gmm_prep<<<MCL, 256, 0, stream>>>(center, L, weight, G, cst);
    gmm_mfma<<<NPTS / BPTS, THREADS, 0, stream>>>(X, G, cst, thr, out);
}